// Round 4
// baseline (263.664 us; speedup 1.0000x reference)
//
#include <hip/hip_runtime.h>

// BinaryAggregationLayer: batch=4096, in_width=8192, out_width=8191.
// out[b][j] = x[b][j] for j<8190; out[b][8190] = 0.5*(x[b][8190]+x[b][8191]);
// clip to +-10000. Memory-bound shifted copy (flat: in = out_idx + b).
//
// ROUND 4 = TIMING PROBE (R3 fixed): launch current kernel (A), then a
// nontemporal variant (B) overwriting the same output with identical values.
// dur_us(R4) - dur_us(R2) == standalone duration of kernel B.
// Fix vs R3: __builtin_nontemporal_* requires a native clang vector type,
// not HIP_vector_type — use ext_vector_type(4) float.

#define OUTW   8191u
#define CLAMPV 10000.0f

typedef float v4f __attribute__((ext_vector_type(4)));

template <bool NT>
__global__ __launch_bounds__(256) void bagg_copy_kernel(
    const float* __restrict__ x, float* __restrict__ out, unsigned int total4) {
    unsigned int t = blockIdx.x * blockDim.x + threadIdx.x;
    if (t >= total4) return;

    unsigned int o0 = t * 4u;                 // flat output index of this quad
    unsigned int b  = o0 / OUTW;              // magic-mul division
    unsigned int j0 = o0 - b * OUTW;

    v4f o4;
    if (j0 < 8187u) {
        unsigned int i0   = o0 + b;           // input flat index of element 0
        unsigned int a    = b & 3u;           // misalignment phase
        unsigned int base = (i0 - a) >> 2;    // aligned float4 index
        const v4f* __restrict__ in4 = reinterpret_cast<const v4f*>(x);
        v4f A, B;
        if (NT) {
            A = __builtin_nontemporal_load(in4 + base);
            B = __builtin_nontemporal_load(in4 + base + 1u);
        } else {
            A = in4[base];
            B = in4[base + 1u];
        }
        if (a == 0u)      o4 = A;
        else if (a == 1u) o4 = (v4f){A.y, A.z, A.w, B.x};
        else if (a == 2u) o4 = (v4f){A.z, A.w, B.x, B.y};
        else              o4 = (v4f){A.w, B.x, B.y, B.z};
    } else {
        // Slow path: j = 8187..8190 (merge node) and wrap into next row.
        float r[4];
        unsigned int j = j0, bb = b;
#pragma unroll
        for (int k = 0; k < 4; ++k) {
            unsigned int i = o0 + (unsigned int)k + bb;
            float v = x[i];
            if (j == OUTW - 1u) v = 0.5f * (v + x[i + 1u]);
            r[k] = v;
            ++j;
            if (j == OUTW) { j = 0u; ++bb; }
        }
        o4 = (v4f){r[0], r[1], r[2], r[3]};
    }

    o4.x = fminf(fmaxf(o4.x, -CLAMPV), CLAMPV);
    o4.y = fminf(fmaxf(o4.y, -CLAMPV), CLAMPV);
    o4.z = fminf(fmaxf(o4.z, -CLAMPV), CLAMPV);
    o4.w = fminf(fmaxf(o4.w, -CLAMPV), CLAMPV);

    if (NT) {
        __builtin_nontemporal_store(o4, reinterpret_cast<v4f*>(out) + t);
    } else {
        reinterpret_cast<v4f*>(out)[t] = o4;
    }
}

extern "C" void kernel_launch(void* const* d_in, const int* in_sizes, int n_in,
                              void* d_out, int out_size, void* d_ws, size_t ws_size,
                              hipStream_t stream) {
    const float* x = (const float*)d_in[0];
    float* out = (float*)d_out;

    const unsigned int total  = 4096u * OUTW;     // 33,550,336
    const unsigned int total4 = total / 4u;       // 8,387,584 (exact)
    const unsigned int block  = 256;
    const unsigned int grid   = (total4 + block - 1) / block;

    // A: the R2 kernel (known end-to-end cost from R2 = 221 us total)
    bagg_copy_kernel<false><<<grid, block, 0, stream>>>(x, out, total4);
    // B: nontemporal variant, rewrites identical values.
    // dur_us(R4) - 221 == T_B (standalone duration of B).
    bagg_copy_kernel<true><<<grid, block, 0, stream>>>(x, out, total4);
}